// Round 1
// baseline (483.792 us; speedup 1.0000x reference)
//
#include <hip/hip_runtime.h>
#include <hip/hip_bf16.h>

#define B_ 8
#define C_ 1536
#define T_ 4096
#define A_ 128
#define K3_ 4608        // 3*C columns of W1
#define CH_ 64          // chunks per row (T/64)

typedef _Float16 h8 __attribute__((ext_vector_type(8)));
typedef float f4 __attribute__((ext_vector_type(4)));

// ---------------- kernel 0: W1 fp32 -> f16 ----------------
__global__ void k0_cvt(const float* __restrict__ W1, _Float16* __restrict__ W1h) {
    int i = blockIdx.x * 256 + threadIdx.x;
    if (i < A_ * K3_) W1h[i] = (_Float16)W1[i];
}

// ---------------- kernel 1: per-(b,c) chunk carries (exclusive prefix of
// masked sum / sumsq at every 64-t chunk boundary) ----------------
__global__ __launch_bounds__(256) void k1_carry(
    const float* __restrict__ x, const int* __restrict__ lens,
    float2* __restrict__ carry)
{
    const int rowid = blockIdx.x * 4 + (threadIdx.x >> 6);
    const int lane  = threadIdx.x & 63;
    const int b     = rowid / C_;
    const int len   = lens[b];
    const float* xr = x + (size_t)rowid * T_;
    float S1 = 0.f, S2 = 0.f;
    const int g = lane >> 4;
    for (int it = 0; it < 16; ++it) {
        const int tb = it * 256 + lane * 4;
        float4 v = *(const float4*)(xr + tb);
        float vals[4] = {v.x, v.y, v.z, v.w};
        float a1 = 0.f, a2 = 0.f;
#pragma unroll
        for (int j = 0; j < 4; ++j) {
            float xv = vals[j];
            float vm = (tb + j < len) ? xv : 0.f;
            a1 += vm; a2 += vm * xv;
        }
        // reduce within 16-lane groups (each group = one 64-t chunk)
#pragma unroll
        for (int d = 1; d < 16; d <<= 1) {
            a1 += __shfl_xor(a1, d, 16);
            a2 += __shfl_xor(a2, d, 16);
        }
        float t10 = __shfl(a1, 0, 64), t11 = __shfl(a1, 16, 64),
              t12 = __shfl(a1, 32, 64), t13 = __shfl(a1, 48, 64);
        float t20 = __shfl(a2, 0, 64), t21 = __shfl(a2, 16, 64),
              t22 = __shfl(a2, 32, 64), t23 = __shfl(a2, 48, 64);
        if ((lane & 15) == 0) {
            float e1 = S1 + (g > 0 ? t10 : 0.f) + (g > 1 ? t11 : 0.f) + (g > 2 ? t12 : 0.f);
            float e2 = S2 + (g > 0 ? t20 : 0.f) + (g > 1 ? t21 : 0.f) + (g > 2 ? t22 : 0.f);
            carry[(size_t)rowid * CH_ + it * 4 + g] = make_float2(e1, e2);
        }
        S1 += t10 + t11 + t12 + t13;
        S2 += t20 + t21 + t22 + t23;
    }
}

// ---------------- kernel 2: fused causal-stats + GEMM(tanh) + W2 -> logits
// block = (b, 64-t chunk), 256 threads = 4 waves.
// LDS tile[t][k] (f16, XOR-swizzled 8-elem k-blocks) holds [x|mean|std] for
// 32 channels; W1 k-slice staged in LDS; mfma_f32_16x16x32_f16.
__global__ __launch_bounds__(256) void k2_gemm(
    const float* __restrict__ x, const int* __restrict__ lens,
    const float2* __restrict__ carry, const _Float16* __restrict__ W1h,
    const float* __restrict__ b1, const float* __restrict__ W2,
    const float* __restrict__ b2, float* __restrict__ logits)
{
    __shared__ _Float16 tile[64][128];   // [t][swizzled k], 16 KB
    __shared__ _Float16 w1t[128][104];   // [a][k 0..95], stride 104 (b128 even)
    __shared__ float s_w2[A_], s_b1[A_];
    __shared__ float lpart[2][64];

    const int tid = threadIdx.x;
    const int b   = blockIdx.x >> 6;
    const int ch  = blockIdx.x & 63;
    const int t0  = ch << 6;
    const int len = lens[b];

    if (tid < A_) { s_w2[tid] = W2[tid]; s_b1[tid] = b1[tid]; }

    const int lane = tid & 63;
    const int w    = tid >> 6;
    const int mtg  = w & 1;      // which half of the 128 a-rows
    const int ntg  = w >> 1;     // which 32-t half of the 64-t tile
    const int ln15 = lane & 15, q = lane >> 4;

    const int r   = tid >> 3;    // 0..31 channel-in-tile (phase A)
    const int seg = tid & 7;     // 8-t segment (phase A)

    f4 acc[4][2] = {};

    for (int c0 = 0; c0 < C_; c0 += 32) {
        // ---- phase A: scan 32 channels x 64 t, emit f16 [x|mean|std] tile
        const int c = c0 + r;
        const size_t row = (size_t)(b * C_ + c);
        const float* xp = x + row * T_ + t0 + seg * 8;
        float4 v0 = *(const float4*)xp;
        float4 v1 = *(const float4*)(xp + 4);
        float xs[8] = {v0.x, v0.y, v0.z, v0.w, v1.x, v1.y, v1.z, v1.w};
        float st1[8], st2[8];
        float run1 = 0.f, run2 = 0.f;
        const int tb = t0 + seg * 8;
#pragma unroll
        for (int j = 0; j < 8; ++j) {
            float xv = xs[j];
            float vm = (tb + j < len) ? xv : 0.f;
            run1 += vm; run2 += vm * xv;
            st1[j] = run1; st2[j] = run2;
        }
        float t1 = run1, t2 = run2;
#pragma unroll
        for (int d = 1; d < 8; d <<= 1) {
            float o1 = __shfl_up(t1, d, 8);
            float o2 = __shfl_up(t2, d, 8);
            if (seg >= d) { t1 += o1; t2 += o2; }
        }
        const float ex1 = t1 - run1, ex2 = t2 - run2;
        const float2 cr = carry[row * CH_ + ch];
#pragma unroll
        for (int j = 0; j < 8; ++j) {
            int t  = tb + j;
            int tl = seg * 8 + j;
            float S1 = cr.x + ex1 + st1[j];
            float S2 = cr.y + ex2 + st2[j];
            float fn = (float)min(t + 1, len);
            float rn = __builtin_amdgcn_rcpf(fn);
            float mean = S1 * rn;
            float var  = S2 * rn - mean * mean;
            float sd   = sqrtf(fmaxf(var, 1e-12f));
            int sw = tl >> 3;   // XOR swizzle of 8-element k-blocks by t-group
            tile[tl][((0 * 4 + (r >> 3)) ^ sw) * 8 + (r & 7)] = (_Float16)xs[j];
            tile[tl][((1 * 4 + (r >> 3)) ^ sw) * 8 + (r & 7)] = (_Float16)mean;
            tile[tl][((2 * 4 + (r >> 3)) ^ sw) * 8 + (r & 7)] = (_Float16)sd;
        }
        // ---- phase B: stage W1 k-slice (128 a x 96 k) into LDS
        {
            const int a  = tid >> 1;
            const int hf = tid & 1;
#pragma unroll
            for (int p = 0; p < 3; ++p) {
                const _Float16* src = W1h + (size_t)a * K3_ + p * C_ + c0 + hf * 16;
                float4 u0 = *(const float4*)src;
                float4 u1 = *(const float4*)(src + 8);
                *(float4*)&w1t[a][p * 32 + hf * 16]     = u0;
                *(float4*)&w1t[a][p * 32 + hf * 16 + 8] = u1;
            }
        }
        __syncthreads();
        // ---- phase C: 24 MFMAs (3 parts x 4 m-tiles x 2 n-tiles)
#pragma unroll
        for (int p = 0; p < 3; ++p) {
            h8 bf[2];
#pragma unroll
            for (int jn = 0; jn < 2; ++jn) {
                int tl  = (ntg * 2 + jn) * 16 + ln15;
                int blk = (p * 4 + q) ^ (tl >> 3);
                bf[jn] = *(const h8*)&tile[tl][blk * 8];
            }
#pragma unroll
            for (int i = 0; i < 4; ++i) {
                int ar = (mtg * 4 + i) * 16 + ln15;
                h8 af = *(const h8*)&w1t[ar][p * 32 + q * 8];
                acc[i][0] = __builtin_amdgcn_mfma_f32_16x16x32_f16(af, bf[0], acc[i][0], 0, 0, 0);
                acc[i][1] = __builtin_amdgcn_mfma_f32_16x16x32_f16(af, bf[1], acc[i][1], 0, 0, 0);
            }
        }
        __syncthreads();
    }
    // ---- epilogue: tanh + W2 reduction -> logits (h never materialized)
    const float b2v = b2[0];
#pragma unroll
    for (int jn = 0; jn < 2; ++jn) {
        float pr = 0.f;
#pragma unroll
        for (int i = 0; i < 4; ++i) {
#pragma unroll
            for (int rg = 0; rg < 4; ++rg) {
                int a = (mtg * 4 + i) * 16 + q * 4 + rg;
                float h = acc[i][jn][rg] + s_b1[a];
                pr += tanhf(h) * s_w2[a];
            }
        }
        pr += __shfl_xor(pr, 16, 64);
        pr += __shfl_xor(pr, 32, 64);
        if (q == 0) lpart[mtg][(ntg * 2 + jn) * 16 + ln15] = pr;
    }
    __syncthreads();
    if (tid < 64) {
        logits[(size_t)b * T_ + t0 + tid] = lpart[0][tid] + lpart[1][tid] + b2v;
    }
}

// ---------------- kernel 3: softmax prep (max, e, cumsum Z) per b ----------
__global__ __launch_bounds__(64) void k3_softmax(
    const float* __restrict__ logits, float* __restrict__ earr,
    float* __restrict__ zarr)
{
    const int b = blockIdx.x;
    const int lane = threadIdx.x;
    const float* lp = logits + (size_t)b * T_;
    float mx = -3.4e38f;
    for (int it = 0; it < 64; ++it) mx = fmaxf(mx, lp[it * 64 + lane]);
#pragma unroll
    for (int d = 1; d < 64; d <<= 1) mx = fmaxf(mx, __shfl_xor(mx, d, 64));
    float run = 0.f;
    for (int it = 0; it < 64; ++it) {
        float ev = expf(lp[it * 64 + lane] - mx);
        float s = ev;
#pragma unroll
        for (int d = 1; d < 64; d <<= 1) {
            float o = __shfl_up(s, d, 64);
            if (lane >= d) s += o;
        }
        earr[(size_t)b * T_ + it * 64 + lane] = ev;
        zarr[(size_t)b * T_ + it * 64 + lane] = run + s;
        run += __shfl(s, 63, 64);
    }
}

// ---------------- kernel 4: weighted running mean/std + final reduce -------
__global__ __launch_bounds__(256) void k4_wstats(
    const float* __restrict__ x, const float* __restrict__ earr,
    const float* __restrict__ zarr, float* __restrict__ out)
{
    const int rowid = blockIdx.x * 4 + (threadIdx.x >> 6);
    const int lane  = threadIdx.x & 63;
    const int b = rowid / C_;
    const int c = rowid - b * C_;
    const float* xr = x + (size_t)rowid * T_;
    const float* er = earr + (size_t)b * T_;
    const float* zr = zarr + (size_t)b * T_;
    float am = 0.f, asd = 0.f, carS = 0.f, carD = 0.f;
    const int g = lane >> 4;
    for (int it = 0; it < 16; ++it) {
        const int tb = it * 256 + lane * 4;
        float4 xv = *(const float4*)(xr + tb);
        float4 ev = *(const float4*)(er + tb);
        float4 zv = *(const float4*)(zr + tb);
        float px[4] = {xv.x, xv.y, xv.z, xv.w};
        float pe[4] = {ev.x, ev.y, ev.z, ev.w};
        float pz[4] = {zv.x, zv.y, zv.z, zv.w};
        float pw[4];
        float s = 0.f;
#pragma unroll
        for (int j = 0; j < 4; ++j) { s += pe[j] * px[j]; pw[j] = s; }
        float totw = s;
        float inc = totw;
#pragma unroll
        for (int d = 1; d < 16; d <<= 1) {
            float o = __shfl_up(inc, d, 16);
            if ((lane & 15) >= d) inc += o;
        }
        float g0 = __shfl(inc, 15, 64), g1 = __shfl(inc, 31, 64);
        float g2 = __shfl(inc, 47, 64), g3 = __shfl(inc, 63, 64);
        float base = carS + (inc - totw)
                   + (g > 0 ? g0 : 0.f) + (g > 1 ? g1 : 0.f) + (g > 2 ? g2 : 0.f);
        carS += g0 + g1 + g2 + g3;
        float wm[4];
#pragma unroll
        for (int j = 0; j < 4; ++j) {
            wm[j] = (base + pw[j]) * __builtin_amdgcn_rcpf(pz[j]);
            am += wm[j];
        }
        float pd[4];
        s = 0.f;
#pragma unroll
        for (int j = 0; j < 4; ++j) {
            float df = px[j] - wm[j];
            s += pe[j] * df * df;
            pd[j] = s;
        }
        float totd = s;
        inc = totd;
#pragma unroll
        for (int d = 1; d < 16; d <<= 1) {
            float o = __shfl_up(inc, d, 16);
            if ((lane & 15) >= d) inc += o;
        }
        g0 = __shfl(inc, 15, 64); g1 = __shfl(inc, 31, 64);
        g2 = __shfl(inc, 47, 64); g3 = __shfl(inc, 63, 64);
        float based = carD + (inc - totd)
                    + (g > 0 ? g0 : 0.f) + (g > 1 ? g1 : 0.f) + (g > 2 ? g2 : 0.f);
        carD += g0 + g1 + g2 + g3;
#pragma unroll
        for (int j = 0; j < 4; ++j) {
            float var = (based + pd[j]) * __builtin_amdgcn_rcpf(pz[j]);
            asd += sqrtf(fmaxf(var, 1e-12f));
        }
    }
#pragma unroll
    for (int d = 1; d < 64; d <<= 1) {
        am  += __shfl_xor(am, d, 64);
        asd += __shfl_xor(asd, d, 64);
    }
    if (lane == 0) {
        out[(size_t)b * (2 * C_) + c]      = am  * (1.f / 4096.f);
        out[(size_t)b * (2 * C_) + C_ + c] = asd * (1.f / 4096.f);
    }
}

extern "C" void kernel_launch(void* const* d_in, const int* in_sizes, int n_in,
                              void* d_out, int out_size, void* d_ws, size_t ws_size,
                              hipStream_t stream) {
    const float* x    = (const float*)d_in[0];
    const int*   lens = (const int*)d_in[1];
    const float* W1   = (const float*)d_in[2];
    const float* b1   = (const float*)d_in[3];
    const float* W2   = (const float*)d_in[4];
    const float* b2   = (const float*)d_in[5];
    float* out = (float*)d_out;

    char* ws = (char*)d_ws;
    // ws layout (7.87 MB total):
    float2*    carry  = (float2*)ws;                    // 8*1536*64*8 = 6,291,456 B
    _Float16*  W1h    = (_Float16*)(ws + 6291456);      // 1,179,648 B
    float*     logits = (float*)(ws + 7471104);         // 131,072 B
    float*     earr   = (float*)(ws + 7602176);         // 131,072 B
    float*     zarr   = (float*)(ws + 7733248);         // 131,072 B

    k0_cvt    <<<(A_ * K3_ + 255) / 256, 256, 0, stream>>>(W1, W1h);
    k1_carry  <<<(B_ * C_) / 4, 256, 0, stream>>>(x, lens, carry);
    k2_gemm   <<<B_ * (T_ / 64), 256, 0, stream>>>(x, lens, carry, W1h, b1, W2, b2, logits);
    k3_softmax<<<B_, 64, 0, stream>>>(logits, earr, zarr);
    k4_wstats <<<(B_ * C_) / 4, 256, 0, stream>>>(x, earr, zarr, out);
}